// Round 15
// baseline (3899.378 us; speedup 1.0000x reference)
//
#include <hip/hip_runtime.h>

#define B_IMG 512
#define C1OFF (-1.2432432432432432f)

typedef __attribute__((ext_vector_type(2))) float f2;
typedef __attribute__((ext_vector_type(4))) float f4;
typedef __attribute__((ext_vector_type(4), aligned(4))) float f4u;

__device__ __forceinline__ float relu_(float v) { return v > 0.f ? v : 0.f; }
__device__ __forceinline__ f2 mk2(float a, float b) { f2 r; r[0] = a; r[1] = b; return r; }

// XCD-aware bijective block swizzle (m204)
__device__ __forceinline__ int swz_block(int bid, int nwg) {
    int q = nwg >> 3, r = nwg & 7;
    int xcd = bid & 7, idx = bid >> 3;
    return (xcd < r ? xcd * (q + 1) : r * (q + 1) + (xcd - r) * q) + idx;
}

// ---- forced packed-fp32 FMA (VOP3P); w uniform -> SGPR pair ----------------
__device__ __forceinline__ f2 pk_fma_sb0(f2 acc, f2 a, f2 b) {
    asm("v_pk_fma_f32 %0, %1, %2, %0 op_sel:[0,0,0] op_sel_hi:[0,1,1]"
        : "+v"(acc) : "s"(a), "v"(b));
    return acc;
}
__device__ __forceinline__ f2 pk_fma_sb1(f2 acc, f2 a, f2 b) {
    asm("v_pk_fma_f32 %0, %1, %2, %0 op_sel:[1,0,0] op_sel_hi:[1,1,1]"
        : "+v"(acc) : "s"(a), "v"(b));
    return acc;
}
__device__ __forceinline__ f2 pk_fma_vb0(f2 acc, f2 a, f2 b) {
    asm("v_pk_fma_f32 %0, %1, %2, %0 op_sel:[0,0,0] op_sel_hi:[0,1,1]"
        : "+v"(acc) : "v"(a), "v"(b));
    return acc;
}
__device__ __forceinline__ f2 pk_fma_vb1(f2 acc, f2 a, f2 b) {
    asm("v_pk_fma_f32 %0, %1, %2, %0 op_sel:[1,0,0] op_sel_hi:[1,1,1]"
        : "+v"(acc) : "v"(a), "v"(b));
    return acc;
}

// ---------------- FC split-K: P[ks] = X[:, ks*720:(ks+1)*720] @ W^T ----------
#define KSPLIT 5
#define KCH 720   // 45 steps of 16

__global__ __launch_bounds__(256) void fc_split(
    const float* __restrict__ X, const float* __restrict__ W,
    float* __restrict__ P)
{
    __shared__ __align__(16) float As[16][68];
    __shared__ __align__(16) float Bs[16][68];
    const int tid = threadIdx.x;
    const int m0 = blockIdx.y * 64;
    const int n0 = blockIdx.x * 64;
    const int ks = blockIdx.z;
    const int kbeg = ks * KCH;
    const int tm = tid >> 4, tn = tid & 15;
    const int lr = tid >> 2;
    const int lk = (tid & 3) << 2;
    const bool bvalid = (n0 + lr) < 3600;
    const float* Arow = X + (size_t)(m0 + lr) * 3600 + lk;
    const float* Brow = W + (size_t)(bvalid ? (n0 + lr) : 0) * 3600 + lk;
    f2 acc2[4][2] = {};
    for (int k0 = kbeg; k0 < kbeg + KCH; k0 += 16) {
        float4 av = *(const float4*)(Arow + k0);
        float4 bv = make_float4(0.f, 0.f, 0.f, 0.f);
        if (bvalid) bv = *(const float4*)(Brow + k0);
        __syncthreads();
        As[lk + 0][lr] = av.x; As[lk + 1][lr] = av.y;
        As[lk + 2][lr] = av.z; As[lk + 3][lr] = av.w;
        Bs[lk + 0][lr] = bv.x; Bs[lk + 1][lr] = bv.y;
        Bs[lk + 2][lr] = bv.z; Bs[lk + 3][lr] = bv.w;
        __syncthreads();
        #pragma unroll
        for (int kk = 0; kk < 16; ++kk) {
            f2 a01 = *(const f2*)&As[kk][tm << 2];
            f2 a23 = *(const f2*)&As[kk][(tm << 2) + 2];
            f2 b01 = *(const f2*)&Bs[kk][tn << 2];
            f2 b23 = *(const f2*)&Bs[kk][(tn << 2) + 2];
            acc2[0][0] = pk_fma_vb0(acc2[0][0], a01, b01);
            acc2[0][1] = pk_fma_vb0(acc2[0][1], a01, b23);
            acc2[1][0] = pk_fma_vb1(acc2[1][0], a01, b01);
            acc2[1][1] = pk_fma_vb1(acc2[1][1], a01, b23);
            acc2[2][0] = pk_fma_vb0(acc2[2][0], a23, b01);
            acc2[2][1] = pk_fma_vb0(acc2[2][1], a23, b23);
            acc2[3][0] = pk_fma_vb1(acc2[3][0], a23, b01);
            acc2[3][1] = pk_fma_vb1(acc2[3][1], a23, b23);
        }
    }
    float* Pk = P + (size_t)ks * 512 * 3600;
    #pragma unroll
    for (int i = 0; i < 4; ++i) {
        int m = m0 + (tm << 2) + i;
        float vals[4] = { acc2[i][0][0], acc2[i][0][1],
                          acc2[i][1][0], acc2[i][1][1] };
        #pragma unroll
        for (int j = 0; j < 4; ++j) {
            int n = n0 + (tn << 2) + j;
            if (n < 3600)
                Pk[(size_t)m * 3600 + n] = vals[j];
        }
    }
}

// reduce partials + bias + relu -> H
__global__ __launch_bounds__(256) void fc_reduce(
    const float* __restrict__ P, const float* __restrict__ Bv,
    float* __restrict__ H)
{
    const size_t TOT = (size_t)512 * 3600;
    size_t i4 = (size_t)blockIdx.x * 256 + threadIdx.x;
    if (i4 >= TOT / 4) return;
    size_t off = i4 * 4;
    f4 s = *(const f4*)(P + off);
    #pragma unroll
    for (int ks = 1; ks < KSPLIT; ++ks) {
        f4 v = *(const f4*)(P + (size_t)ks * TOT + off);
        s[0] += v[0]; s[1] += v[1]; s[2] += v[2]; s[3] += v[3];
    }
    int n = (int)(off % 3600);
    f4u bv = *(const f4u*)(Bv + n);
    s[0] = relu_(s[0] + bv[0]); s[1] = relu_(s[1] + bv[1]);
    s[2] = relu_(s[2] + bv[2]); s[3] = relu_(s[3] + bv[3]);
    *(f4*)(H + off) = s;
}

// ------- weight prep: fp32 (OC,IC,9,9) -> fp32 pairs -------------------------
__global__ __launch_bounds__(256) void prep_pk(
    const float* __restrict__ w, int OC, int IC, f2* __restrict__ out)
{
    int n = IC * 9 * OC * 5;
    for (int t = threadIdx.x + blockIdx.x * 256; t < n; t += gridDim.x * 256) {
        int m = t % 5; int rest = t / 5;
        int oc = rest % OC; rest /= OC;
        int ky = rest % 9; int ic = rest / 9;
        const float* ws = w + (((size_t)oc * IC + ic) * 9 + ky) * 9;
        float lo = ws[2 * m];
        float hi = (2 * m + 1 < 9) ? ws[2 * m + 1] : 0.f;
        out[t] = mk2(lo, hi);
    }
}

// ---------------- padding formula (build_padded fused) -----------------------
__device__ __forceinline__ float pad_core(const float* __restrict__ xb,
                                          const float* __restrict__ hb,
                                          int ch, int r, int c)
{
    if (r < 16) return 0.f;
    int rr = (r <= 75) ? r : (151 - r);
    int cc = (c <= 75) ? c : (151 - c);
    int i = rr - 16, j = cc - 16;
    if (ch == 0) return xb[i * 60 + j];
    if (ch == 1) return hb[i * 60 + j];
    return (j >= 51) ? 1.0f : ((j >= 41) ? 0.5f : 0.0f);
}

__device__ __forceinline__ float pad_val(const float* __restrict__ xb,
                                         const float* __restrict__ hb,
                                         int ch, int r, int c)
{
    if (c >= 16) return pad_core(xb, hb, ch, r, c);
    float v = pad_core(xb, hb, ch, r, 31 - c);
    return (ch == 1) ? (C1OFF - v) : v;
}

#define PADN 25392   // 3*92*92 per image
#define CH1OFF 8464  // channel stride in pad canvas

__global__ __launch_bounds__(256) void pad02_kernel(
    const float* __restrict__ x, float* __restrict__ pad)
{
    const int b = blockIdx.x;
    const float* xb = x + (size_t)b * 3600;
    float* pb = pad + (size_t)b * PADN;
    for (int i = threadIdx.x; i < 2 * 8464; i += 256) {
        int cs = i / 8464;
        int rem = i - cs * 8464;
        int r = rem / 92;
        int c = rem - r * 92;
        int ch = cs * 2;
        pb[(size_t)ch * CH1OFF + rem] = pad_val(xb, nullptr, ch, r, c);
    }
}

__global__ __launch_bounds__(256) void padh_kernel(
    const float* __restrict__ h, float* __restrict__ pad)
{
    const int b = blockIdx.x;
    const float* hb = h + (size_t)b * 3600;
    float* pb = pad + (size_t)b * PADN + CH1OFF;
    for (int i = threadIdx.x; i < 8464; i += 256) {
        int r = i / 92;
        int c = i - r * 92;
        pb[i] = pad_val(nullptr, hb, 1, r, c);
    }
}

// Build re/sh pairs from 3 ALIGNED dwordx4 loads; then PIN them with an
// empty-asm keep-live barrier so the register allocator cannot re-materialize
// the pair construction inside the oc loop (r14: VGPR=36 proved it rebuilt
// sh per-oc -> 1.7x VALU inflation).
#define MKPAIRS(row_)                                                         \
    f4 e0 = *(const f4*)(row_);                                               \
    f4 e1 = *(const f4*)((row_) + 4);                                         \
    f4 e2 = *(const f4*)((row_) + 8);                                         \
    f2 re[6], sh[5];                                                          \
    re[0] = mk2(e0[0], e0[1]); re[1] = mk2(e0[2], e0[3]);                     \
    re[2] = mk2(e1[0], e1[1]); re[3] = mk2(e1[2], e1[3]);                     \
    re[4] = mk2(e2[0], e2[1]); re[5] = mk2(e2[2], e2[3]);                     \
    sh[0] = mk2(e0[1], e0[2]); sh[1] = mk2(e0[3], e1[0]);                     \
    sh[2] = mk2(e1[1], e1[2]); sh[3] = mk2(e1[3], e2[0]);                     \
    sh[4] = mk2(e2[1], e2[2]);                                                \
    asm volatile("" : "+v"(re[0]), "+v"(re[1]), "+v"(re[2]), "+v"(re[3]),     \
                      "+v"(re[4]), "+v"(re[5]), "+v"(sh[0]), "+v"(sh[1]),     \
                      "+v"(sh[2]), "+v"(sh[3]), "+v"(sh[4]));

// ---- convP: 1-row x 4 cols, pk_fma, s-weights -------------------------------
template<int IC, int OC, int IH, bool RELU, bool INIT>
__global__ __launch_bounds__(256, 3) void convP(
    const float* __restrict__ in, const f2* __restrict__ wpk,
    const float* __restrict__ bias, const float* __restrict__ basep,
    float* __restrict__ out, int total, int istride, int chstride, int wstride)
{
    constexpr int IW = IH, OH = IH - 8, OW = OH;
    constexpr int NGX = OW / 4, NPB = OH * NGX;
    const int sb = swz_block(blockIdx.x, gridDim.x);
    const int p0 = sb * 256 + threadIdx.x;
    const bool act = (p0 < total);
    const int p = act ? p0 : (total - 1);
    const int b = p / NPB;
    const int rem = p - b * NPB;
    const int oy = rem / NGX;
    const int x0 = (rem - oy * NGX) * 4;
    const float* ib = in + (size_t)b * istride + (size_t)oy * IW + x0;

    f2 acc[OC][2];
    if (INIT) {
        #pragma unroll
        for (int oc = 0; oc < OC; ++oc) {
            const float* bp = basep + ((size_t)b * OC + oc) * (OH * OW)
                              + (size_t)oy * OW + x0;
            f4 v = *(const f4*)bp;
            acc[oc][0] = mk2(v[0], v[1]);
            acc[oc][1] = mk2(v[2], v[3]);
        }
    } else {
        #pragma unroll
        for (int oc = 0; oc < OC; ++oc) {
            float bv = bias[oc];
            acc[oc][0] = mk2(bv, bv);
            acc[oc][1] = mk2(bv, bv);
        }
    }

    #pragma unroll 1
    for (int ic = 0; ic < IC; ++ic) {
        const float* rp = ib + (size_t)ic * chstride;
        const f2* wq0 = wpk + (size_t)ic * wstride;
        #pragma unroll
        for (int ky = 0; ky < 9; ++ky) {
            const float* row = rp + ky * IW;
            MKPAIRS(row)
            const f2* wq = wq0 + ky * OC * 5;
            #pragma unroll
            for (int oc = 0; oc < OC; ++oc) {
                const f2* w5 = wq + oc * 5;
                #pragma unroll
                for (int m = 0; m < 4; ++m) {
                    f2 w = w5[m];
                    acc[oc][0] = pk_fma_sb0(acc[oc][0], w, re[m]);
                    acc[oc][0] = pk_fma_sb1(acc[oc][0], w, sh[m]);
                    acc[oc][1] = pk_fma_sb0(acc[oc][1], w, re[m + 1]);
                    acc[oc][1] = pk_fma_sb1(acc[oc][1], w, sh[m + 1]);
                }
                f2 w4v = w5[4];
                acc[oc][0] = pk_fma_sb0(acc[oc][0], w4v, re[4]);
                acc[oc][1] = pk_fma_sb0(acc[oc][1], w4v, re[5]);
            }
        }
    }

    if (act) {
        #pragma unroll
        for (int oc = 0; oc < OC; ++oc) {
            float* ob = out + ((size_t)b * OC + oc) * (OH * OW)
                        + (size_t)oy * OW + x0;
            float v0 = acc[oc][0][0], v1 = acc[oc][0][1];
            float v2 = acc[oc][1][0], v3 = acc[oc][1][1];
            if (RELU) { v0 = relu_(v0); v1 = relu_(v1); v2 = relu_(v2); v3 = relu_(v3); }
            *(float4*)ob = make_float4(v0, v1, v2, v3);
        }
    }
}

// ---- convP2: 2 rows x 4 cols, rolling rows ----------------------------------
#define LOADROW(RE, SH, KY)                                                   \
    do {                                                                      \
        const float* row_ = rp + (KY) * IW;                                   \
        f4 e0_ = *(const f4*)(row_);                                          \
        f4 e1_ = *(const f4*)(row_ + 4);                                      \
        f4 e2_ = *(const f4*)(row_ + 8);                                      \
        RE[0] = mk2(e0_[0], e0_[1]); RE[1] = mk2(e0_[2], e0_[3]);             \
        RE[2] = mk2(e1_[0], e1_[1]); RE[3] = mk2(e1_[2], e1_[3]);             \
        RE[4] = mk2(e2_[0], e2_[1]); RE[5] = mk2(e2_[2], e2_[3]);             \
        SH[0] = mk2(e0_[1], e0_[2]); SH[1] = mk2(e0_[3], e1_[0]);             \
        SH[2] = mk2(e1_[1], e1_[2]); SH[3] = mk2(e1_[3], e2_[0]);             \
        SH[4] = mk2(e2_[1], e2_[2]);                                          \
        asm volatile("" : "+v"(RE[0]), "+v"(RE[1]), "+v"(RE[2]),              \
                          "+v"(RE[3]), "+v"(RE[4]), "+v"(RE[5]),              \
                          "+v"(SH[0]), "+v"(SH[1]), "+v"(SH[2]),              \
                          "+v"(SH[3]), "+v"(SH[4]));                          \
    } while (0)

#define FMASTEP(TRE, TSH, BRE, BSH, KY)                                       \
    do {                                                                      \
        const f2* wq_ = wq0 + (KY) * OC * 5;                                  \
        _Pragma("unroll")                                                     \
        for (int oc = 0; oc < OC; ++oc) {                                     \
            const f2* w5_ = wq_ + oc * 5;                                     \
            _Pragma("unroll")                                                 \
            for (int m = 0; m < 4; ++m) {                                     \
                f2 w_ = w5_[m];                                               \
                acc[oc][0][0] = pk_fma_sb0(acc[oc][0][0], w_, TRE[m]);        \
                acc[oc][0][0] = pk_fma_sb1(acc[oc][0][0], w_, TSH[m]);        \
                acc[oc][0][1] = pk_fma_sb0(acc[oc][0][1], w_, TRE[m + 1]);    \
                acc[oc][0][1] = pk_fma_sb1(acc[oc][0][1], w_, TSH[m + 1]);    \
                acc[oc][1][0] = pk_fma_sb0(acc[oc][1][0], w_, BRE[m]);        \
                acc[oc][1][0] = pk_fma_sb1(acc[oc][1][0], w_, BSH[m]);        \
                acc[oc][1][1] = pk_fma_sb0(acc[oc][1][1], w_, BRE[m + 1]);    \
                acc[oc][1][1] = pk_fma_sb1(acc[oc][1][1], w_, BSH[m + 1]);    \
            }                                                                 \
            f2 w4_ = w5_[4];                                                  \
            acc[oc][0][0] = pk_fma_sb0(acc[oc][0][0], w4_, TRE[4]);           \
            acc[oc][0][1] = pk_fma_sb0(acc[oc][0][1], w4_, TRE[5]);           \
            acc[oc][1][0] = pk_fma_sb0(acc[oc][1][0], w4_, BRE[4]);           \
            acc[oc][1][1] = pk_fma_sb0(acc[oc][1][1], w4_, BRE[5]);           \
        }                                                                     \
    } while (0)

#define STEP(TRE, TSH, BRE, BSH, KY)                                          \
    do { LOADROW(BRE, BSH, (KY) + 1); FMASTEP(TRE, TSH, BRE, BSH, KY); } while (0)

template<int IC, int OC, int IH, bool RELU, bool INIT>
__global__ __launch_bounds__(256, 2) void convP2(
    const float* __restrict__ in, const f2* __restrict__ wpk,
    const float* __restrict__ bias, const float* __restrict__ basep,
    float* __restrict__ out, int total, int istride, int chstride, int wstride)
{
    constexpr int IW = IH, OH = IH - 8, OW = OH;
    constexpr int NGX = OW / 4, NGY = OH / 2, NPB = NGX * NGY;
    const int sb = swz_block(blockIdx.x, gridDim.x);
    const int p0 = sb * 256 + threadIdx.x;
    const bool act = (p0 < total);
    const int p = act ? p0 : (total - 1);
    const int b = p / NPB;
    const int rem = p - b * NPB;
    const int gy = rem / NGX;
    const int gx = rem - gy * NGX;
    const int oy = gy * 2, x0 = gx * 4;
    const float* ib = in + (size_t)b * istride + (size_t)oy * IW + x0;

    f2 acc[OC][2][2];
    if (INIT) {
        #pragma unroll
        for (int oc = 0; oc < OC; ++oc) {
            const float* bp = basep + ((size_t)b * OC + oc) * (OH * OW)
                              + (size_t)oy * OW + x0;
            f4 v0 = *(const f4*)bp;
            f4 v1 = *(const f4*)(bp + OW);
            acc[oc][0][0] = mk2(v0[0], v0[1]); acc[oc][0][1] = mk2(v0[2], v0[3]);
            acc[oc][1][0] = mk2(v1[0], v1[1]); acc[oc][1][1] = mk2(v1[2], v1[3]);
        }
    } else {
        #pragma unroll
        for (int oc = 0; oc < OC; ++oc) {
            float bv = bias[oc];
            acc[oc][0][0] = mk2(bv, bv); acc[oc][0][1] = mk2(bv, bv);
            acc[oc][1][0] = mk2(bv, bv); acc[oc][1][1] = mk2(bv, bv);
        }
    }

    #pragma unroll 1
    for (int ic = 0; ic < IC; ++ic) {
        const float* rp = ib + (size_t)ic * chstride;
        const f2* wq0 = wpk + (size_t)ic * wstride;
        f2 reA[6], shA[5], reB[6], shB[5];
        LOADROW(reA, shA, 0);
        STEP(reA, shA, reB, shB, 0);
        STEP(reB, shB, reA, shA, 1);
        STEP(reA, shA, reB, shB, 2);
        STEP(reB, shB, reA, shA, 3);
        STEP(reA, shA, reB, shB, 4);
        STEP(reB, shB, reA, shA, 5);
        STEP(reA, shA, reB, shB, 6);
        STEP(reB, shB, reA, shA, 7);
        STEP(reA, shA, reB, shB, 8);
    }

    if (act) {
        #pragma unroll
        for (int oc = 0; oc < OC; ++oc) {
            float* ob = out + ((size_t)b * OC + oc) * (OH * OW)
                        + (size_t)oy * OW + x0;
            float v0 = acc[oc][0][0][0], v1 = acc[oc][0][0][1];
            float v2 = acc[oc][0][1][0], v3 = acc[oc][0][1][1];
            float u0 = acc[oc][1][0][0], u1 = acc[oc][1][0][1];
            float u2 = acc[oc][1][1][0], u3 = acc[oc][1][1][1];
            if (RELU) {
                v0 = relu_(v0); v1 = relu_(v1); v2 = relu_(v2); v3 = relu_(v3);
                u0 = relu_(u0); u1 = relu_(u1); u2 = relu_(u2); u3 = relu_(u3);
            }
            *(float4*)&ob[0]  = make_float4(v0, v1, v2, v3);
            *(float4*)&ob[OW] = make_float4(u0, u1, u2, u3);
        }
    }
}

extern "C" void kernel_launch(void* const* d_in, const int* in_sizes, int n_in,
                              void* d_out, int out_size, void* d_ws, size_t ws_size,
                              hipStream_t stream)
{
    const float* x   = (const float*)d_in[0];
    const float* fcw = (const float*)d_in[1];
    const float* fcb = (const float*)d_in[2];
    const float* w1  = (const float*)d_in[3];
    const float* b1  = (const float*)d_in[4];
    const float* w2  = (const float*)d_in[5];
    const float* b2  = (const float*)d_in[6];
    const float* w3  = (const float*)d_in[7];
    const float* b3  = (const float*)d_in[8];
    const float* w4  = (const float*)d_in[9];
    const float* b4  = (const float*)d_in[10];

    float* h = (float*)d_out;   // h lives in d_out (512*3600)

    // ws: packed weights (128 KB) | region shared by {FC partials} then
    // {pad | base | t1 | t2} — lifetimes disjoint, so they alias.
    f2* wp1 = (f2*)d_ws;                 // 3*9*8*5 = 1080
    f2* wp2 = wp1 + 4096;                // 8*9*8*5 = 2880
    f2* wp3 = wp2 + 4096;
    f2* wp4 = wp3 + 4096;                // 8*9*1*5 = 360
    float* region = (float*)((char*)d_ws + 131072);
    size_t avail = (ws_size - 131072) / sizeof(float);

    float* fcp = region;                 // KSPLIT*512*3600 floats (36.9 MB)

    const size_t T1N = 8 * 84 * 84;   // 56448 (also base1 size)
    const size_t T2N = 8 * 76 * 76;   // 46208
    size_t per_img = PADN + T1N + T1N + T2N;
    int CHN = (int)(avail / per_img);
    if (CHN > B_IMG) CHN = B_IMG;
    if (CHN < 1) CHN = 1;
    float* pad  = region;
    float* bse  = pad + (size_t)CHN * PADN;
    float* t1   = bse + (size_t)CHN * T1N;
    float* t2   = t1 + (size_t)CHN * T1N;

    prep_pk<<<5, 256, 0, stream>>>(w1, 8, 3, wp1);
    prep_pk<<<12, 256, 0, stream>>>(w2, 8, 8, wp2);
    prep_pk<<<12, 256, 0, stream>>>(w3, 8, 8, wp3);
    prep_pk<<<2, 256, 0, stream>>>(w4, 1, 8, wp4);

    fc_split<<<dim3(57, 8, KSPLIT), 256, 0, stream>>>(x, fcw, fcp);
    fc_reduce<<<1800, 256, 0, stream>>>(fcp, fcb, h);

    for (int c0 = 0; c0 < B_IMG; c0 += CHN) {
        int cn = (B_IMG - c0) < CHN ? (B_IMG - c0) : CHN;
        pad02_kernel<<<cn, 256, 0, stream>>>(x + (size_t)c0 * 3600, pad);
        int tb = cn * 882;   // 42*21 2-row patches (92->84)
        convP2<2, 8, 92, false, false><<<(tb + 255) / 256, 256, 0, stream>>>(
            pad, wp1, b1, nullptr, bse, tb, PADN, 2 * CH1OFF, 2 * 360);
        for (int it = 0; it < 5; ++it) {
            padh_kernel<<<cn, 256, 0, stream>>>(h + (size_t)c0 * 3600, pad);
            int t1n = cn * 882;    // conv1h: 2-row patches
            int t2n = cn * 1444;   // conv2: 1-row (76*19)
            int t3n = cn * 1156;   // conv3: 1-row (68*17)
            int t4n = cn * 450;    // conv4: 2-row (30*15)
            convP2<1, 8, 92, true, true><<<(t1n + 255) / 256, 256, 0, stream>>>(
                pad + CH1OFF, wp1 + 360, nullptr, bse, t1, t1n, PADN, 0, 0);
            convP<8, 8, 84, true, false><<<(t2n + 255) / 256, 256, 0, stream>>>(
                t1, wp2, b2, nullptr, t2, t2n, (int)T1N, 84 * 84, 360);
            convP<8, 8, 76, true, false><<<(t3n + 255) / 256, 256, 0, stream>>>(
                t2, wp3, b3, nullptr, t1, t3n, (int)T2N, 76 * 76, 360);
            convP2<8, 1, 68, false, false><<<(t4n + 255) / 256, 256, 0, stream>>>(
                t1, wp4, b4, nullptr, h + (size_t)c0 * 3600, t4n,
                8 * 68 * 68, 68 * 68, 45);
        }
    }
}

// Round 16
// 3535.612 us; speedup vs baseline: 1.1029x; 1.1029x over previous
//
#include <hip/hip_runtime.h>

#define B_IMG 512
#define C1OFF (-1.2432432432432432f)

typedef __attribute__((ext_vector_type(2))) float f2;
typedef __attribute__((ext_vector_type(4))) float f4;
typedef __attribute__((ext_vector_type(4), aligned(4))) float f4u;

__device__ __forceinline__ float relu_(float v) { return v > 0.f ? v : 0.f; }
__device__ __forceinline__ f2 mk2(float a, float b) { f2 r; r[0] = a; r[1] = b; return r; }

// XCD-aware bijective block swizzle (m204)
__device__ __forceinline__ int swz_block(int bid, int nwg) {
    int q = nwg >> 3, r = nwg & 7;
    int xcd = bid & 7, idx = bid >> 3;
    return (xcd < r ? xcd * (q + 1) : r * (q + 1) + (xcd - r) * q) + idx;
}

// ---- forced packed-fp32 FMA (VOP3P); w uniform -> SGPR pair ----------------
__device__ __forceinline__ f2 pk_fma_sb0(f2 acc, f2 a, f2 b) {
    asm("v_pk_fma_f32 %0, %1, %2, %0 op_sel:[0,0,0] op_sel_hi:[0,1,1]"
        : "+v"(acc) : "s"(a), "v"(b));
    return acc;
}
__device__ __forceinline__ f2 pk_fma_sb1(f2 acc, f2 a, f2 b) {
    asm("v_pk_fma_f32 %0, %1, %2, %0 op_sel:[1,0,0] op_sel_hi:[1,1,1]"
        : "+v"(acc) : "s"(a), "v"(b));
    return acc;
}
__device__ __forceinline__ f2 pk_fma_vb0(f2 acc, f2 a, f2 b) {
    asm("v_pk_fma_f32 %0, %1, %2, %0 op_sel:[0,0,0] op_sel_hi:[0,1,1]"
        : "+v"(acc) : "v"(a), "v"(b));
    return acc;
}
__device__ __forceinline__ f2 pk_fma_vb1(f2 acc, f2 a, f2 b) {
    asm("v_pk_fma_f32 %0, %1, %2, %0 op_sel:[1,0,0] op_sel_hi:[1,1,1]"
        : "+v"(acc) : "v"(a), "v"(b));
    return acc;
}

// ---------------- FC split-K: P[ks] = X[:, ks*720:(ks+1)*720] @ W^T ----------
#define KSPLIT 5
#define KCH 720   // 45 steps of 16

__global__ __launch_bounds__(256) void fc_split(
    const float* __restrict__ X, const float* __restrict__ W,
    float* __restrict__ P)
{
    __shared__ __align__(16) float As[16][68];
    __shared__ __align__(16) float Bs[16][68];
    const int tid = threadIdx.x;
    const int m0 = blockIdx.y * 64;
    const int n0 = blockIdx.x * 64;
    const int ks = blockIdx.z;
    const int kbeg = ks * KCH;
    const int tm = tid >> 4, tn = tid & 15;
    const int lr = tid >> 2;
    const int lk = (tid & 3) << 2;
    const bool bvalid = (n0 + lr) < 3600;
    const float* Arow = X + (size_t)(m0 + lr) * 3600 + lk;
    const float* Brow = W + (size_t)(bvalid ? (n0 + lr) : 0) * 3600 + lk;
    f2 acc2[4][2] = {};
    for (int k0 = kbeg; k0 < kbeg + KCH; k0 += 16) {
        float4 av = *(const float4*)(Arow + k0);
        float4 bv = make_float4(0.f, 0.f, 0.f, 0.f);
        if (bvalid) bv = *(const float4*)(Brow + k0);
        __syncthreads();
        As[lk + 0][lr] = av.x; As[lk + 1][lr] = av.y;
        As[lk + 2][lr] = av.z; As[lk + 3][lr] = av.w;
        Bs[lk + 0][lr] = bv.x; Bs[lk + 1][lr] = bv.y;
        Bs[lk + 2][lr] = bv.z; Bs[lk + 3][lr] = bv.w;
        __syncthreads();
        #pragma unroll
        for (int kk = 0; kk < 16; ++kk) {
            f2 a01 = *(const f2*)&As[kk][tm << 2];
            f2 a23 = *(const f2*)&As[kk][(tm << 2) + 2];
            f2 b01 = *(const f2*)&Bs[kk][tn << 2];
            f2 b23 = *(const f2*)&Bs[kk][(tn << 2) + 2];
            acc2[0][0] = pk_fma_vb0(acc2[0][0], a01, b01);
            acc2[0][1] = pk_fma_vb0(acc2[0][1], a01, b23);
            acc2[1][0] = pk_fma_vb1(acc2[1][0], a01, b01);
            acc2[1][1] = pk_fma_vb1(acc2[1][1], a01, b23);
            acc2[2][0] = pk_fma_vb0(acc2[2][0], a23, b01);
            acc2[2][1] = pk_fma_vb0(acc2[2][1], a23, b23);
            acc2[3][0] = pk_fma_vb1(acc2[3][0], a23, b01);
            acc2[3][1] = pk_fma_vb1(acc2[3][1], a23, b23);
        }
    }
    float* Pk = P + (size_t)ks * 512 * 3600;
    #pragma unroll
    for (int i = 0; i < 4; ++i) {
        int m = m0 + (tm << 2) + i;
        float vals[4] = { acc2[i][0][0], acc2[i][0][1],
                          acc2[i][1][0], acc2[i][1][1] };
        #pragma unroll
        for (int j = 0; j < 4; ++j) {
            int n = n0 + (tn << 2) + j;
            if (n < 3600)
                Pk[(size_t)m * 3600 + n] = vals[j];
        }
    }
}

// reduce partials + bias + relu -> H
__global__ __launch_bounds__(256) void fc_reduce(
    const float* __restrict__ P, const float* __restrict__ Bv,
    float* __restrict__ H)
{
    const size_t TOT = (size_t)512 * 3600;
    size_t i4 = (size_t)blockIdx.x * 256 + threadIdx.x;
    if (i4 >= TOT / 4) return;
    size_t off = i4 * 4;
    f4 s = *(const f4*)(P + off);
    #pragma unroll
    for (int ks = 1; ks < KSPLIT; ++ks) {
        f4 v = *(const f4*)(P + (size_t)ks * TOT + off);
        s[0] += v[0]; s[1] += v[1]; s[2] += v[2]; s[3] += v[3];
    }
    int n = (int)(off % 3600);
    f4u bv = *(const f4u*)(Bv + n);
    s[0] = relu_(s[0] + bv[0]); s[1] = relu_(s[1] + bv[1]);
    s[2] = relu_(s[2] + bv[2]); s[3] = relu_(s[3] + bv[3]);
    *(f4*)(H + off) = s;
}

// ------- weight prep: fp32 (OC,IC,9,9) -> fp32 pairs -------------------------
__global__ __launch_bounds__(256) void prep_pk(
    const float* __restrict__ w, int OC, int IC, f2* __restrict__ out)
{
    int n = IC * 9 * OC * 5;
    for (int t = threadIdx.x + blockIdx.x * 256; t < n; t += gridDim.x * 256) {
        int m = t % 5; int rest = t / 5;
        int oc = rest % OC; rest /= OC;
        int ky = rest % 9; int ic = rest / 9;
        const float* ws = w + (((size_t)oc * IC + ic) * 9 + ky) * 9;
        float lo = ws[2 * m];
        float hi = (2 * m + 1 < 9) ? ws[2 * m + 1] : 0.f;
        out[t] = mk2(lo, hi);
    }
}

// ---------------- padding formula (build_padded fused) -----------------------
__device__ __forceinline__ float pad_core(const float* __restrict__ xb,
                                          const float* __restrict__ hb,
                                          int ch, int r, int c)
{
    if (r < 16) return 0.f;
    int rr = (r <= 75) ? r : (151 - r);
    int cc = (c <= 75) ? c : (151 - c);
    int i = rr - 16, j = cc - 16;
    if (ch == 0) return xb[i * 60 + j];
    if (ch == 1) return hb[i * 60 + j];
    return (j >= 51) ? 1.0f : ((j >= 41) ? 0.5f : 0.0f);
}

__device__ __forceinline__ float pad_val(const float* __restrict__ xb,
                                         const float* __restrict__ hb,
                                         int ch, int r, int c)
{
    if (c >= 16) return pad_core(xb, hb, ch, r, c);
    float v = pad_core(xb, hb, ch, r, 31 - c);
    return (ch == 1) ? (C1OFF - v) : v;
}

#define PADN 25392   // 3*92*92 per image
#define CH1OFF 8464  // channel stride in pad canvas

// once per chunk: channels 0 (x), 2 (ff), and the h-independent top rows of ch1
__global__ __launch_bounds__(256) void pad02_kernel(
    const float* __restrict__ x, float* __restrict__ pad)
{
    const int b = blockIdx.x;
    const float* xb = x + (size_t)b * 3600;
    float* pb = pad + (size_t)b * PADN;
    const int N02 = 2 * 8464;
    const int NTOP = 16 * 92;
    for (int i = threadIdx.x; i < N02 + NTOP; i += 256) {
        if (i < N02) {
            int cs = i / 8464;
            int rem = i - cs * 8464;
            int r = rem / 92;
            int c = rem - r * 92;
            int ch = cs * 2;
            pb[(size_t)ch * CH1OFF + rem] = pad_val(xb, nullptr, ch, r, c);
        } else {
            int j = i - N02;
            int r = j / 92;
            int c = j - r * 92;
            pb[CH1OFF + r * 92 + c] = (c < 16) ? C1OFF : 0.f;  // ch1 top rows
        }
    }
}

// per chunk (initial only): channel 1 (h) rows >= 16 from FC's h
__global__ __launch_bounds__(256) void padh_kernel(
    const float* __restrict__ h, float* __restrict__ pad)
{
    const int b = blockIdx.x;
    const float* hb = h + (size_t)b * 3600;
    float* pb = pad + (size_t)b * PADN + CH1OFF;
    for (int i = threadIdx.x; i < 8464; i += 256) {
        int r = i / 92;
        int c = i - r * 92;
        if (r >= 16) pb[i] = pad_val(nullptr, hb, 1, r, c);
    }
}

// Build re/sh pairs from 3 ALIGNED dwordx4 loads only (no shifted loads).
#define MKPAIRS(row_)                                                         \
    f4 e0 = *(const f4*)(row_);                                               \
    f4 e1 = *(const f4*)((row_) + 4);                                         \
    f4 e2 = *(const f4*)((row_) + 8);                                         \
    f2 re[6], sh[5];                                                          \
    re[0] = mk2(e0[0], e0[1]); re[1] = mk2(e0[2], e0[3]);                     \
    re[2] = mk2(e1[0], e1[1]); re[3] = mk2(e1[2], e1[3]);                     \
    re[4] = mk2(e2[0], e2[1]); re[5] = mk2(e2[2], e2[3]);                     \
    sh[0] = mk2(e0[1], e0[2]); sh[1] = mk2(e0[3], e1[0]);                     \
    sh[2] = mk2(e1[1], e1[2]); sh[3] = mk2(e1[3], e2[0]);                     \
    sh[4] = mk2(e2[1], e2[2]);

// ---- convP: 1-row x 4 cols, pk_fma, s-weights -------------------------------
template<int IC, int OC, int IH, bool RELU, bool INIT>
__global__ __launch_bounds__(256, 3) void convP(
    const float* __restrict__ in, const f2* __restrict__ wpk,
    const float* __restrict__ bias, const float* __restrict__ basep,
    float* __restrict__ out, int total, int istride, int chstride, int wstride)
{
    constexpr int IW = IH, OH = IH - 8, OW = OH;
    constexpr int NGX = OW / 4, NPB = OH * NGX;
    const int sb = swz_block(blockIdx.x, gridDim.x);
    const int p0 = sb * 256 + threadIdx.x;
    const bool act = (p0 < total);
    const int p = act ? p0 : (total - 1);
    const int b = p / NPB;
    const int rem = p - b * NPB;
    const int oy = rem / NGX;
    const int x0 = (rem - oy * NGX) * 4;
    const float* ib = in + (size_t)b * istride + (size_t)oy * IW + x0;

    f2 acc[OC][2];
    if (INIT) {
        #pragma unroll
        for (int oc = 0; oc < OC; ++oc) {
            const float* bp = basep + ((size_t)b * OC + oc) * (OH * OW)
                              + (size_t)oy * OW + x0;
            f4 v = *(const f4*)bp;
            acc[oc][0] = mk2(v[0], v[1]);
            acc[oc][1] = mk2(v[2], v[3]);
        }
    } else {
        #pragma unroll
        for (int oc = 0; oc < OC; ++oc) {
            float bv = bias[oc];
            acc[oc][0] = mk2(bv, bv);
            acc[oc][1] = mk2(bv, bv);
        }
    }

    #pragma unroll 1
    for (int ic = 0; ic < IC; ++ic) {
        const float* rp = ib + (size_t)ic * chstride;
        const f2* wq0 = wpk + (size_t)ic * wstride;
        #pragma unroll
        for (int ky = 0; ky < 9; ++ky) {
            const float* row = rp + ky * IW;
            MKPAIRS(row)
            const f2* wq = wq0 + ky * OC * 5;
            #pragma unroll
            for (int oc = 0; oc < OC; ++oc) {
                const f2* w5 = wq + oc * 5;
                #pragma unroll
                for (int m = 0; m < 4; ++m) {
                    f2 w = w5[m];
                    acc[oc][0] = pk_fma_sb0(acc[oc][0], w, re[m]);
                    acc[oc][0] = pk_fma_sb1(acc[oc][0], w, sh[m]);
                    acc[oc][1] = pk_fma_sb0(acc[oc][1], w, re[m + 1]);
                    acc[oc][1] = pk_fma_sb1(acc[oc][1], w, sh[m + 1]);
                }
                f2 w4v = w5[4];
                acc[oc][0] = pk_fma_sb0(acc[oc][0], w4v, re[4]);
                acc[oc][1] = pk_fma_sb0(acc[oc][1], w4v, re[5]);
            }
        }
    }

    if (act) {
        #pragma unroll
        for (int oc = 0; oc < OC; ++oc) {
            float* ob = out + ((size_t)b * OC + oc) * (OH * OW)
                        + (size_t)oy * OW + x0;
            float v0 = acc[oc][0][0], v1 = acc[oc][0][1];
            float v2 = acc[oc][1][0], v3 = acc[oc][1][1];
            if (RELU) { v0 = relu_(v0); v1 = relu_(v1); v2 = relu_(v2); v3 = relu_(v3); }
            *(float4*)ob = make_float4(v0, v1, v2, v3);
        }
    }
}

// ---- convP2: 2 rows x 4 cols, rolling rows ----------------------------------
#define LOADROW(RE, SH, KY)                                                   \
    do {                                                                      \
        const float* row_ = rp + (KY) * IW;                                   \
        f4 e0_ = *(const f4*)(row_);                                          \
        f4 e1_ = *(const f4*)(row_ + 4);                                      \
        f4 e2_ = *(const f4*)(row_ + 8);                                      \
        RE[0] = mk2(e0_[0], e0_[1]); RE[1] = mk2(e0_[2], e0_[3]);             \
        RE[2] = mk2(e1_[0], e1_[1]); RE[3] = mk2(e1_[2], e1_[3]);             \
        RE[4] = mk2(e2_[0], e2_[1]); RE[5] = mk2(e2_[2], e2_[3]);             \
        SH[0] = mk2(e0_[1], e0_[2]); SH[1] = mk2(e0_[3], e1_[0]);             \
        SH[2] = mk2(e1_[1], e1_[2]); SH[3] = mk2(e1_[3], e2_[0]);             \
        SH[4] = mk2(e2_[1], e2_[2]);                                          \
    } while (0)

#define FMASTEP(TRE, TSH, BRE, BSH, KY)                                       \
    do {                                                                      \
        const f2* wq_ = wq0 + (KY) * OC * 5;                                  \
        _Pragma("unroll")                                                     \
        for (int oc = 0; oc < OC; ++oc) {                                     \
            const f2* w5_ = wq_ + oc * 5;                                     \
            _Pragma("unroll")                                                 \
            for (int m = 0; m < 4; ++m) {                                     \
                f2 w_ = w5_[m];                                               \
                acc[oc][0][0] = pk_fma_sb0(acc[oc][0][0], w_, TRE[m]);        \
                acc[oc][0][0] = pk_fma_sb1(acc[oc][0][0], w_, TSH[m]);        \
                acc[oc][0][1] = pk_fma_sb0(acc[oc][0][1], w_, TRE[m + 1]);    \
                acc[oc][0][1] = pk_fma_sb1(acc[oc][0][1], w_, TSH[m + 1]);    \
                acc[oc][1][0] = pk_fma_sb0(acc[oc][1][0], w_, BRE[m]);        \
                acc[oc][1][0] = pk_fma_sb1(acc[oc][1][0], w_, BSH[m]);        \
                acc[oc][1][1] = pk_fma_sb0(acc[oc][1][1], w_, BRE[m + 1]);    \
                acc[oc][1][1] = pk_fma_sb1(acc[oc][1][1], w_, BSH[m + 1]);    \
            }                                                                 \
            f2 w4_ = w5_[4];                                                  \
            acc[oc][0][0] = pk_fma_sb0(acc[oc][0][0], w4_, TRE[4]);           \
            acc[oc][0][1] = pk_fma_sb0(acc[oc][0][1], w4_, TRE[5]);           \
            acc[oc][1][0] = pk_fma_sb0(acc[oc][1][0], w4_, BRE[4]);           \
            acc[oc][1][1] = pk_fma_sb0(acc[oc][1][1], w4_, BRE[5]);           \
        }                                                                     \
    } while (0)

#define STEP(TRE, TSH, BRE, BSH, KY)                                          \
    do { LOADROW(BRE, BSH, (KY) + 1); FMASTEP(TRE, TSH, BRE, BSH, KY); } while (0)

template<int IC, int OC, int IH, bool RELU, bool INIT>
__global__ __launch_bounds__(256, 2) void convP2(
    const float* __restrict__ in, const f2* __restrict__ wpk,
    const float* __restrict__ bias, const float* __restrict__ basep,
    float* __restrict__ out, int total, int istride, int chstride, int wstride)
{
    constexpr int IW = IH, OH = IH - 8, OW = OH;
    constexpr int NGX = OW / 4, NGY = OH / 2, NPB = NGX * NGY;
    const int sb = swz_block(blockIdx.x, gridDim.x);
    const int p0 = sb * 256 + threadIdx.x;
    const bool act = (p0 < total);
    const int p = act ? p0 : (total - 1);
    const int b = p / NPB;
    const int rem = p - b * NPB;
    const int gy = rem / NGX;
    const int gx = rem - gy * NGX;
    const int oy = gy * 2, x0 = gx * 4;
    const float* ib = in + (size_t)b * istride + (size_t)oy * IW + x0;

    f2 acc[OC][2][2];
    if (INIT) {
        #pragma unroll
        for (int oc = 0; oc < OC; ++oc) {
            const float* bp = basep + ((size_t)b * OC + oc) * (OH * OW)
                              + (size_t)oy * OW + x0;
            f4 v0 = *(const f4*)bp;
            f4 v1 = *(const f4*)(bp + OW);
            acc[oc][0][0] = mk2(v0[0], v0[1]); acc[oc][0][1] = mk2(v0[2], v0[3]);
            acc[oc][1][0] = mk2(v1[0], v1[1]); acc[oc][1][1] = mk2(v1[2], v1[3]);
        }
    } else {
        #pragma unroll
        for (int oc = 0; oc < OC; ++oc) {
            float bv = bias[oc];
            acc[oc][0][0] = mk2(bv, bv); acc[oc][0][1] = mk2(bv, bv);
            acc[oc][1][0] = mk2(bv, bv); acc[oc][1][1] = mk2(bv, bv);
        }
    }

    #pragma unroll 1
    for (int ic = 0; ic < IC; ++ic) {
        const float* rp = ib + (size_t)ic * chstride;
        const f2* wq0 = wpk + (size_t)ic * wstride;
        f2 reA[6], shA[5], reB[6], shB[5];
        LOADROW(reA, shA, 0);
        STEP(reA, shA, reB, shB, 0);
        STEP(reB, shB, reA, shA, 1);
        STEP(reA, shA, reB, shB, 2);
        STEP(reB, shB, reA, shA, 3);
        STEP(reA, shA, reB, shB, 4);
        STEP(reB, shB, reA, shA, 5);
        STEP(reA, shA, reB, shB, 6);
        STEP(reB, shB, reA, shA, 7);
        STEP(reA, shA, reB, shB, 8);
    }

    if (act) {
        #pragma unroll
        for (int oc = 0; oc < OC; ++oc) {
            float* ob = out + ((size_t)b * OC + oc) * (OH * OW)
                        + (size_t)oy * OW + x0;
            float v0 = acc[oc][0][0][0], v1 = acc[oc][0][0][1];
            float v2 = acc[oc][0][1][0], v3 = acc[oc][0][1][1];
            float u0 = acc[oc][1][0][0], u1 = acc[oc][1][0][1];
            float u2 = acc[oc][1][1][0], u3 = acc[oc][1][1][1];
            if (RELU) {
                v0 = relu_(v0); v1 = relu_(v1); v2 = relu_(v2); v3 = relu_(v3);
                u0 = relu_(u0); u1 = relu_(u1); u2 = relu_(u2); u3 = relu_(u3);
            }
            *(float4*)&ob[0]  = make_float4(v0, v1, v2, v3);
            *(float4*)&ob[OW] = make_float4(u0, u1, u2, u3);
        }
    }
}

// ---- convP4: conv4 (8->1) fused with pad-ch1 scatter (replaces padh) --------
// inverse mirror map per h cell (hr,hc): interior (16+hr,16+hc);
// left (hc<=15): (.,15-hc)=C1OFF-v; right (hc>=44): (.,135-hc)=v;
// bottom (hr>=44): row 135-hr copies of the above.
__global__ __launch_bounds__(256, 2) void convP4(
    const float* __restrict__ in, const f2* __restrict__ wpk,
    const float* __restrict__ bias, float* __restrict__ hout,
    float* __restrict__ pad, int total)
{
    constexpr int OC = 1;
    constexpr int IH = 68, IW = 68, OW = 60;
    constexpr int NGX = 15, NPB = 450;
    const int sb = swz_block(blockIdx.x, gridDim.x);
    const int p0 = sb * 256 + threadIdx.x;
    const bool act = (p0 < total);
    const int p = act ? p0 : (total - 1);
    const int b = p / NPB;
    const int rem = p - b * NPB;
    const int gy = rem / NGX;
    const int gx = rem - gy * NGX;
    const int oy = gy * 2, x0 = gx * 4;
    const float* ib = in + (size_t)b * (8 * 68 * 68) + (size_t)oy * IW + x0;

    f2 acc[OC][2][2];
    float bv = bias[0];
    acc[0][0][0] = mk2(bv, bv); acc[0][0][1] = mk2(bv, bv);
    acc[0][1][0] = mk2(bv, bv); acc[0][1][1] = mk2(bv, bv);

    #pragma unroll 1
    for (int ic = 0; ic < 8; ++ic) {
        const float* rp = ib + (size_t)ic * (68 * 68);
        const f2* wq0 = wpk + (size_t)ic * 45;
        f2 reA[6], shA[5], reB[6], shB[5];
        LOADROW(reA, shA, 0);
        STEP(reA, shA, reB, shB, 0);
        STEP(reB, shB, reA, shA, 1);
        STEP(reA, shA, reB, shB, 2);
        STEP(reB, shB, reA, shA, 3);
        STEP(reA, shA, reB, shB, 4);
        STEP(reB, shB, reA, shA, 5);
        STEP(reA, shA, reB, shB, 6);
        STEP(reB, shB, reA, shA, 7);
        STEP(reA, shA, reB, shB, 8);
    }

    if (act) {
        float vals[2][4] = {
            { acc[0][0][0][0], acc[0][0][0][1], acc[0][0][1][0], acc[0][0][1][1] },
            { acc[0][1][0][0], acc[0][1][0][1], acc[0][1][1][0], acc[0][1][1][1] } };
        float* hb = hout + (size_t)b * 3600 + (size_t)oy * OW + x0;
        *(float4*)&hb[0]  = make_float4(vals[0][0], vals[0][1], vals[0][2], vals[0][3]);
        *(float4*)&hb[OW] = make_float4(vals[1][0], vals[1][1], vals[1][2], vals[1][3]);
        float* pb = pad + (size_t)b * PADN + CH1OFF;
        #pragma unroll
        for (int r2 = 0; r2 < 2; ++r2) {
            int hr = oy + r2;
            *(float4*)&pb[(16 + hr) * 92 + 16 + x0] =
                make_float4(vals[r2][0], vals[r2][1], vals[r2][2], vals[r2][3]);
            #pragma unroll
            for (int j = 0; j < 4; ++j) {
                int hc = x0 + j; float v = vals[r2][j];
                if (hc <= 15) pb[(16 + hr) * 92 + 15 - hc] = C1OFF - v;
                if (hc >= 44) pb[(16 + hr) * 92 + 135 - hc] = v;
            }
            if (hr >= 44) {
                int qr = 135 - hr;
                #pragma unroll
                for (int j = 0; j < 4; ++j) {
                    int hc = x0 + j; float v = vals[r2][j];
                    pb[qr * 92 + 16 + hc] = v;
                    if (hc <= 15) pb[qr * 92 + 15 - hc] = C1OFF - v;
                    if (hc >= 44) pb[qr * 92 + 135 - hc] = v;
                }
            }
        }
    }
}

extern "C" void kernel_launch(void* const* d_in, const int* in_sizes, int n_in,
                              void* d_out, int out_size, void* d_ws, size_t ws_size,
                              hipStream_t stream)
{
    const float* x   = (const float*)d_in[0];
    const float* fcw = (const float*)d_in[1];
    const float* fcb = (const float*)d_in[2];
    const float* w1  = (const float*)d_in[3];
    const float* b1  = (const float*)d_in[4];
    const float* w2  = (const float*)d_in[5];
    const float* b2  = (const float*)d_in[6];
    const float* w3  = (const float*)d_in[7];
    const float* b3  = (const float*)d_in[8];
    const float* w4  = (const float*)d_in[9];
    const float* b4  = (const float*)d_in[10];

    float* h = (float*)d_out;   // h lives in d_out (512*3600)

    // ws: packed weights (128 KB) | region shared by {FC partials} then
    // {pad | base | t1 | t2} — lifetimes disjoint, so they alias.
    f2* wp1 = (f2*)d_ws;                 // 3*9*8*5 = 1080
    f2* wp2 = wp1 + 4096;                // 8*9*8*5 = 2880
    f2* wp3 = wp2 + 4096;
    f2* wp4 = wp3 + 4096;                // 8*9*1*5 = 360
    float* region = (float*)((char*)d_ws + 131072);
    size_t avail = (ws_size - 131072) / sizeof(float);

    float* fcp = region;                 // KSPLIT*512*3600 floats (36.9 MB)

    const size_t T1N = 8 * 84 * 84;   // 56448 (also base1 size)
    const size_t T2N = 8 * 76 * 76;   // 46208
    size_t per_img = PADN + T1N + T1N + T2N;
    int CHN = (int)(avail / per_img);
    if (CHN > B_IMG) CHN = B_IMG;
    if (CHN < 1) CHN = 1;
    float* pad  = region;
    float* bse  = pad + (size_t)CHN * PADN;
    float* t1   = bse + (size_t)CHN * T1N;
    float* t2   = t1 + (size_t)CHN * T1N;

    prep_pk<<<5, 256, 0, stream>>>(w1, 8, 3, wp1);
    prep_pk<<<12, 256, 0, stream>>>(w2, 8, 8, wp2);
    prep_pk<<<12, 256, 0, stream>>>(w3, 8, 8, wp3);
    prep_pk<<<2, 256, 0, stream>>>(w4, 1, 8, wp4);

    fc_split<<<dim3(57, 8, KSPLIT), 256, 0, stream>>>(x, fcw, fcp);
    fc_reduce<<<1800, 256, 0, stream>>>(fcp, fcb, h);

    for (int c0 = 0; c0 < B_IMG; c0 += CHN) {
        int cn = (B_IMG - c0) < CHN ? (B_IMG - c0) : CHN;
        pad02_kernel<<<cn, 256, 0, stream>>>(x + (size_t)c0 * 3600, pad);
        int tb = cn * 882;   // 42*21 2-row patches (92->84)
        convP2<2, 8, 92, false, false><<<(tb + 255) / 256, 256, 0, stream>>>(
            pad, wp1, b1, nullptr, bse, tb, PADN, 2 * CH1OFF, 2 * 360);
        padh_kernel<<<cn, 256, 0, stream>>>(h + (size_t)c0 * 3600, pad);
        for (int it = 0; it < 5; ++it) {
            int t1n = cn * 882;    // conv1h: 2-row patches
            int t2n = cn * 1444;   // conv2: 1-row (76*19)
            int t3n = cn * 1156;   // conv3: 1-row (68*17)
            int t4n = cn * 450;    // conv4: 2-row (30*15)
            convP2<1, 8, 92, true, true><<<(t1n + 255) / 256, 256, 0, stream>>>(
                pad + CH1OFF, wp1 + 360, nullptr, bse, t1, t1n, PADN, 0, 0);
            convP<8, 8, 84, true, false><<<(t2n + 255) / 256, 256, 0, stream>>>(
                t1, wp2, b2, nullptr, t2, t2n, (int)T1N, 84 * 84, 360);
            convP<8, 8, 76, true, false><<<(t3n + 255) / 256, 256, 0, stream>>>(
                t2, wp3, b3, nullptr, t1, t3n, (int)T2N, 76 * 76, 360);
            convP4<<<(t4n + 255) / 256, 256, 0, stream>>>(
                t1, wp4, b4, h + (size_t)c0 * 3600, pad, t4n);
        }
    }
}